// Round 6
// baseline (65832.855 us; speedup 1.0000x reference)
//
#include <hip/hip_runtime.h>
#include <math.h>

// ---------------- problem constants ----------------
#define BSZ   64
#define NXDIM 729
#define NXP   736          // padded (multiple of 16), pad cols are zero
#define MDIM  324
#define MP    328          // padded vector length for m-dim arrays
#define LDA   328          // ADAT leading dim (doubles)
#define EPS   0.1
#define SIG   0.1
#define NIT   30

// Cholesky blocking
#define NB    36
#define NPAN  9            // 324 / 36
#define CTHR  1024
#define PSTR  360          // P panel stride: 324 + 36 zero pad (tile reads overshoot <= +30)

// ADAT tiling: 64x64 tiles over 6x6 upper -> 21 pairs, vector f64 FMA
#define AKC   16
#define ANCH  46           // 736 / 16

typedef unsigned long long ull;

// ---------------- setup kernels ----------------

__global__ void k_setupA(const float* __restrict__ Af,
                         double* __restrict__ A64, double* __restrict__ AT64) {
  int idx = blockIdx.x * 256 + threadIdx.x;
  if (idx < MDIM * NXP) {
    int r = idx / NXP, c = idx % NXP;
    A64[idx] = (c < NXDIM) ? (double)Af[r * NXDIM + c] : 0.0;
  }
  if (idx < NXP * MP) {
    int i = idx / MP, m = idx % MP;
    AT64[idx] = (i < NXDIM && m < MDIM) ? (double)Af[m * NXDIM + i] : 0.0;
  }
}

__global__ void k_setupState(const float* __restrict__ puz,
                             double* __restrict__ p, double* __restrict__ z,
                             double* __restrict__ lam, double* __restrict__ dd,
                             double* __restrict__ nu) {
  int idx = blockIdx.x * 256 + threadIdx.x;
  if (idx >= BSZ * NXP) return;
  int b = idx / NXP, i = idx % NXP;
  p[idx]   = (i < NXDIM) ? -(double)puz[b * NXDIM + i] : 0.0;
  z[idx]   = 1.0;
  lam[idx] = 1.0;
  dd[idx]  = 0.0;              // pads (i>=729) must stay 0 for k_adat
  if (i < MP) nu[b * MP + i] = 0.0;
}

__global__ void k_setupB(const double* __restrict__ A64,
                         const float* __restrict__ lz, double* __restrict__ bvec) {
  int m = blockIdx.x, tid = threadIdx.x;
  __shared__ double red[256];
  double s = 0.0;
  for (int i = tid; i < NXDIM; i += 256)
    s += A64[m * NXP + i] * exp((double)lz[i]);
  red[tid] = s; __syncthreads();
  for (int w = 128; w > 0; w >>= 1) { if (tid < w) red[tid] += red[tid + w]; __syncthreads(); }
  if (tid == 0) bvec[m] = red[0];
}

// ---------------- per-iteration kernels ----------------

// Fused mu + stage1 (rz,rc,d,g) + rhs. One 1024-thread WG per batch.
__global__ __launch_bounds__(1024) void k_pre(const double* __restrict__ A64,
                                              const double* __restrict__ AT64,
                                              const double* __restrict__ z,
                                              const double* __restrict__ lam,
                                              const double* __restrict__ nu,
                                              const double* __restrict__ p,
                                              const double* __restrict__ bvec,
                                              double* __restrict__ mu_g,
                                              double* __restrict__ dd,
                                              double* __restrict__ g,
                                              double* __restrict__ rhs) {
  int b = blockIdx.x, tid = threadIdx.x;
  __shared__ double nus[MDIM];
  __shared__ double zs[NXDIM];
  __shared__ double dgs[NXDIM];
  __shared__ double red[CTHR];
  __shared__ double smu;
  double s = 0.0;
  for (int l = tid; l < NXDIM; l += CTHR) {
    double zv = z[b * NXP + l], lv = lam[b * NXP + l];
    zs[l] = zv; s += zv * lv;
  }
  for (int l = tid; l < MDIM; l += CTHR) nus[l] = nu[b * MP + l];
  red[tid] = s; __syncthreads();
  for (int w = 512; w > 0; w >>= 1) { if (tid < w) red[tid] += red[tid + w]; __syncthreads(); }
  if (tid == 0) { smu = red[0] / (double)NXDIM; mu_g[b] = smu; }
  __syncthreads();
  double muv = smu;
  if (tid < NXDIM) {
    int i = tid;
    double acc = 0.0;
    #pragma unroll 4
    for (int m = 0; m < MDIM; ++m) acc += A64[m * NXP + i] * nus[m];
    double zv = zs[i], lv = lam[b * NXP + i], pv = p[b * NXP + i];
    double rz = EPS * zv + pv - lv + acc;
    double rc = zv * lv - SIG * muv;
    double ddv = 1.0 / (EPS + lv / zv);
    double gv = -(rz + rc / zv);
    dd[b * NXP + i] = ddv;
    g[b * NXP + i]  = gv;
    dgs[i] = ddv * gv;
  }
  __syncthreads();
  if (tid < MDIM) {
    double a1 = 0.0, a2 = 0.0;
    #pragma unroll 4
    for (int i = 0; i < NXDIM; ++i) {
      double a = AT64[i * MP + tid];
      a1 += a * zs[i];
      a2 += a * dgs[i];
    }
    rhs[b * MP + tid] = a2 + a1 - bvec[tid];
  }
}

// ADAT[b] upper 64x64 tile pairs, vector f64 FMA. Block = 256 thr, 4x4/thread,
// strided ownership: rows {ty+16r}, cols {tx+16c} -> conflict-free LDS reads.
__global__ __launch_bounds__(256) void k_adat(const double* __restrict__ A64,
                                              const double* __restrict__ dd,
                                              double* __restrict__ ADAT) {
  int pr = blockIdx.x;   // 0..20 upper tile pairs of 6x6 tiling
  int b  = blockIdx.y;
  int ti = 0, prr = pr;
  while (prr >= 6 - ti) { prr -= 6 - ti; ti++; }
  int tj = ti + prr;
  int m0 = ti * 64, n0 = tj * 64;
  __shared__ double Sa[AKC][66];   // [k][row] transposed
  __shared__ double Sb[AKC][66];
  int tid = threadIdx.x;
  int tx = tid & 15, ty = tid >> 4;
  const double* db = dd + b * NXP;
  double acc[4][4];
  #pragma unroll
  for (int r = 0; r < 4; ++r)
    #pragma unroll
    for (int c = 0; c < 4; ++c) acc[r][c] = 0.0;

  #pragma unroll 1
  for (int ch = 0; ch < ANCH; ++ch) {
    int i0 = ch * AKC;
    __syncthreads();
    #pragma unroll
    for (int q = 0; q < 4; ++q) {
      int row = ty + q * 16;
      int mrow = m0 + row, nrow = n0 + row;
      Sa[tx][row] = (mrow < MDIM) ? A64[(size_t)mrow * NXP + i0 + tx] : 0.0;
      Sb[tx][row] = (nrow < MDIM) ? A64[(size_t)nrow * NXP + i0 + tx] * db[i0 + tx] : 0.0;
    }
    __syncthreads();
    #pragma unroll
    for (int k = 0; k < AKC; ++k) {
      double ra[4], rb[4];
      #pragma unroll
      for (int r = 0; r < 4; ++r) ra[r] = Sa[k][ty + 16 * r];
      #pragma unroll
      for (int c = 0; c < 4; ++c) rb[c] = Sb[k][tx + 16 * c];
      #pragma unroll
      for (int r = 0; r < 4; ++r)
        #pragma unroll
        for (int c = 0; c < 4; ++c) acc[r][c] += ra[r] * rb[c];
    }
  }
  double* Mb = ADAT + (size_t)b * LDA * LDA;
  #pragma unroll
  for (int r = 0; r < 4; ++r) {
    int m = m0 + ty + 16 * r;
    if (m >= MDIM) continue;
    #pragma unroll
    for (int c = 0; c < 4; ++c) {
      int n = n0 + tx + 16 * c;
      if (n < MDIM) Mb[(size_t)m * LDA + n] = acc[r][c];
    }
  }
}

// Blocked upper Cholesky (U^T U) + solve, one 1024-thread WG (16 waves) per batch.
// NB=36 (9 panels): halves trailing-C global traffic vs NB=18.
// Diag factor: wave-0 shfl recurrence. Trailing: 32x32 tile/wave, 4x4 regs/lane.
__global__ __launch_bounds__(1024) void k_chol(double* __restrict__ ADAT,
                                               const double* __restrict__ rhs,
                                               double* __restrict__ dnu) {
  int b = blockIdx.x, tid = threadIdx.x;
  int lane = tid & 63, wid = tid >> 6;      // 16 waves
  double* Mb = ADAT + (size_t)b * LDA * LDA;
  __shared__ double P[NB][PSTR];   // panel rows U[k0+t][j], abs col idx; [324,360) zero
  __shared__ double D[NB][NB + 1]; // diagonal block
  __shared__ double yv[MDIM];      // rhs -> y -> x
  __shared__ double ivp[NB];
  __shared__ double ys[NB];

  for (int l = tid; l < NB * (PSTR - MDIM); l += CTHR) {
    int r = l / (PSTR - MDIM), c = l % (PSTR - MDIM);
    P[r][MDIM + c] = 0.0;          // zero pad columns once; never written again
  }
  for (int l = tid; l < MDIM; l += CTHR) yv[l] = rhs[b * MP + l];

  #pragma unroll 1
  for (int p = 0; p < NPAN; ++p) {
    int k0 = p * NB, t0 = k0 + NB, rem = MDIM - t0;
    __syncthreads();
    // ---- load diag block cooperatively (NB*NB = 1296 > 1024: loop!) ----
    for (int l = tid; l < NB * NB; l += CTHR) {
      int r = l / NB, c = l % NB;
      D[r][c] = Mb[(size_t)(k0 + r) * LDA + (k0 + c)];
    }
    __syncthreads();
    // ---- factor diag block: wave 0, shfl recurrence (no barriers inside) ----
    if (wid == 0) {
      double dreg[NB];
      #pragma unroll
      for (int r = 0; r < NB; ++r) dreg[r] = (lane < NB) ? D[r][lane] : 0.0;
      double myiv = 0.0;
      #pragma unroll 1
      for (int kk = 0; kk < NB; ++kk) {
        double dk = __shfl(dreg[kk], kk);
        double iv = 1.0 / sqrt(dk);
        double u  = dreg[kk] * iv;     // row kk scaled: U[kk][lane]
        dreg[kk] = u;
        if (lane == kk) myiv = iv;
        for (int r = kk + 1; r < NB; ++r)
          dreg[r] -= __shfl(u, r) * u; // rank-1: D[r][lane] -= U[kk][r]*U[kk][lane]
      }
      if (lane < NB) {
        ivp[lane] = myiv;
        #pragma unroll
        for (int r = 0; r < NB; ++r) {
          D[r][lane] = dreg[r];
          if (r <= lane) Mb[(size_t)(k0 + r) * LDA + (k0 + lane)] = dreg[r];
        }
      }
    }
    __syncthreads();
    // ---- panel rows (triangular solves, barrier-free) + fused fwd-subst col ----
    {
      bool isY = (tid == rem);
      bool act = (tid < rem) || isY;
      int j = t0 + tid;
      if (act) {
        double val[NB];
        #pragma unroll 1
        for (int r = 0; r < NB; ++r) {
          double v = isY ? yv[k0 + r] : Mb[(size_t)(k0 + r) * LDA + j];
          for (int t = 0; t < r; ++t) v -= D[t][r] * val[t];
          v *= ivp[r];
          val[r] = v;
          if (isY) { ys[r] = v; yv[k0 + r] = v; }
          else     { P[r][j] = v; Mb[(size_t)(k0 + r) * LDA + j] = v; }
        }
      }
    }
    __syncthreads();
    if (rem <= 0) continue;
    // ---- y tail update ----
    if (tid < rem) {
      int j = t0 + tid;
      double s = yv[j];
      #pragma unroll
      for (int t = 0; t < NB; ++t) s -= P[t][j] * ys[t];
      yv[j] = s;
    }
    // ---- trailing update: 32x32 tile per wave, 4x4 regs per lane ----
    {
      int Ni = (rem + 31) >> 5;
      int cnt = Ni * (Ni + 1) / 2;
      for (int tt = wid; tt < cnt; tt += 16) {
        int a = 0, r2 = tt;
        while (r2 >= Ni - a) { r2 -= Ni - a; ++a; }
        int bb = a + r2;
        int i0 = t0 + 32 * a, j0 = t0 + 32 * bb;
        int ib = i0 + (lane >> 3);   // rows ib + 8r
        int jb = j0 + (lane & 7);    // cols jb + 8c
        bool full = (i0 + 31 < MDIM) && (j0 + 31 < MDIM);
        double cv[4][4];
        if (full) {
          #pragma unroll
          for (int r = 0; r < 4; ++r)
            #pragma unroll
            for (int c = 0; c < 4; ++c)
              cv[r][c] = Mb[(size_t)(ib + 8 * r) * LDA + (jb + 8 * c)];
        } else {
          #pragma unroll
          for (int r = 0; r < 4; ++r)
            #pragma unroll
            for (int c = 0; c < 4; ++c) {
              int i = ib + 8 * r, j = jb + 8 * c;
              cv[r][c] = (i < MDIM && j < MDIM) ? Mb[(size_t)i * LDA + j] : 0.0;
            }
        }
        #pragma unroll
        for (int t = 0; t < NB; ++t) {
          double pi[4], pj[4];
          #pragma unroll
          for (int r = 0; r < 4; ++r) pi[r] = P[t][ib + 8 * r];
          #pragma unroll
          for (int c = 0; c < 4; ++c) pj[c] = P[t][jb + 8 * c];
          #pragma unroll
          for (int r = 0; r < 4; ++r)
            #pragma unroll
            for (int c = 0; c < 4; ++c) cv[r][c] -= pi[r] * pj[c];
        }
        if (full && bb > a) {        // strictly upper tile: unguarded store
          #pragma unroll
          for (int r = 0; r < 4; ++r)
            #pragma unroll
            for (int c = 0; c < 4; ++c)
              Mb[(size_t)(ib + 8 * r) * LDA + (jb + 8 * c)] = cv[r][c];
        } else {
          #pragma unroll
          for (int r = 0; r < 4; ++r)
            #pragma unroll
            for (int c = 0; c < 4; ++c) {
              int i = ib + 8 * r, j = jb + 8 * c;
              if (i < MDIM && j < MDIM && j >= i) Mb[(size_t)i * LDA + j] = cv[r][c];
            }
        }
      }
    }
  }
  // ---- back substitution: U x = y ----
  #pragma unroll 1
  for (int p = NPAN - 1; p >= 0; --p) {
    int k0 = p * NB, t0 = k0 + NB;
    __syncthreads();
    for (int l = tid; l < NB * NB; l += CTHR) {
      int r = l / NB, c = l % NB;
      D[r][c] = Mb[(size_t)(k0 + r) * LDA + (k0 + c)];
    }
    __syncthreads();
    if (t0 < MDIM) {  // y[k0+r] -= sum_{j>=t0} U[k0+r][j] * x[j]
      for (int r = wid; r < NB; r += 16) {
        double s = 0.0;
        for (int j = t0 + lane; j < MDIM; j += 64)
          s += Mb[(size_t)(k0 + r) * LDA + j] * yv[j];
        for (int off = 32; off > 0; off >>= 1) s += __shfl_xor(s, off);
        if (lane == 0) yv[k0 + r] -= s;
      }
    }
    __syncthreads();
    if (tid < 64) {   // wave-0 shfl-based diagonal back-solve (lanes 0..35 hold cols)
      double accv = 0.0;
      for (int kk = NB - 1; kk >= 0; --kk) {
        double ad = __shfl(accv, kk);
        double xkk = (yv[k0 + kk] - ad) / D[kk][kk];
        if (lane < kk) accv += D[lane][kk] * xkk;
        if (lane == kk) yv[k0 + kk] = xkk;
      }
    }
  }
  __syncthreads();
  for (int l = tid; l < MDIM; l += CTHR) dnu[b * MP + l] = yv[l];
}

// Fused step+update: dz/dlam in registers, in-WG alpha reduction, apply.
__global__ __launch_bounds__(1024) void k_post(const double* __restrict__ A64,
                                               const double* __restrict__ dnu,
                                               const double* __restrict__ dd,
                                               const double* __restrict__ g,
                                               const double* __restrict__ mu_g,
                                               double* __restrict__ z,
                                               double* __restrict__ lam,
                                               double* __restrict__ nu) {
  int b = blockIdx.x, tid = threadIdx.x;
  int lane = tid & 63, wid = tid >> 6;
  __shared__ double ds[MDIM];
  __shared__ double wmin[16];
  __shared__ double salpha;
  for (int l = tid; l < MDIM; l += CTHR) ds[l] = dnu[b * MP + l];
  __syncthreads();
  double zv = 0.0, lv = 0.0, dzv = 0.0, dlv = 0.0;
  bool act = (tid < NXDIM);
  double inf = __builtin_inf();
  double rm = inf;
  if (act) {
    int i = tid;
    double acc = 0.0;
    #pragma unroll 4
    for (int m = 0; m < MDIM; ++m) acc += A64[m * NXP + i] * ds[m];
    zv = z[b * NXP + i]; lv = lam[b * NXP + i];
    double ddv = dd[b * NXP + i], gv = g[b * NXP + i];
    dzv = ddv * (gv - acc);
    double rc = zv * lv - SIG * mu_g[b];
    dlv = -(rc + lv * dzv) / zv;
    double r1 = (dzv < 0.0) ? (-zv / dzv) : inf;
    double r2 = (dlv < 0.0) ? (-lv / dlv) : inf;
    rm = fmin(r1, r2);
  }
  for (int off = 32; off > 0; off >>= 1) rm = fmin(rm, __shfl_xor(rm, off));
  if (lane == 0) wmin[wid] = rm;
  __syncthreads();
  if (tid == 0) {
    double a = wmin[0];
    #pragma unroll
    for (int w = 1; w < 16; ++w) a = fmin(a, wmin[w]);
    salpha = fmin(1.0, 0.99 * a);
  }
  __syncthreads();
  double a = salpha;
  if (act) {
    z[b * NXP + tid]   = zv + a * dzv;
    lam[b * NXP + tid] = lv + a * dlv;
  }
  if (tid < MDIM) nu[b * MP + tid] += a * ds[tid];
}

__global__ void k_out(const double* __restrict__ z, float* __restrict__ out) {
  int idx = blockIdx.x * 256 + threadIdx.x;
  if (idx >= BSZ * NXDIM) return;
  int b = idx / NXDIM, i = idx % NXDIM;
  out[idx] = (float)z[b * NXP + i];
}

// ---------------- host launcher ----------------

extern "C" void kernel_launch(void* const* d_in, const int* in_sizes, int n_in,
                              void* d_out, int out_size, void* d_ws, size_t ws_size,
                              hipStream_t stream) {
  const float* puz = (const float*)d_in[0];
  const float* Af  = (const float*)d_in[1];
  const float* lz  = (const float*)d_in[2];
  float* out = (float*)d_out;

  char* base = (char*)d_ws;
  size_t off = 0;
  auto alloc = [&](size_t bytes) -> void* {
    void* ptr = base + off;
    off = (off + bytes + 255) & ~(size_t)255;
    return ptr;
  };
  double* A64  = (double*)alloc((size_t)MDIM * NXP * 8);
  double* AT64 = (double*)alloc((size_t)NXP * MP * 8);
  double* p_   = (double*)alloc((size_t)BSZ * NXP * 8);
  double* z_   = (double*)alloc((size_t)BSZ * NXP * 8);
  double* lam_ = (double*)alloc((size_t)BSZ * NXP * 8);
  double* dd_  = (double*)alloc((size_t)BSZ * NXP * 8);
  double* g_   = (double*)alloc((size_t)BSZ * NXP * 8);
  double* nu_  = (double*)alloc((size_t)BSZ * MP * 8);
  double* dnu_ = (double*)alloc((size_t)BSZ * MP * 8);
  double* rhs_ = (double*)alloc((size_t)BSZ * MP * 8);
  double* bvec = (double*)alloc((size_t)MP * 8);
  double* mu_  = (double*)alloc((size_t)BSZ * 8);
  double* ADAT = (double*)alloc((size_t)BSZ * LDA * LDA * 8);
  (void)ws_size; (void)in_sizes; (void)n_in; (void)out_size;

  k_setupA<<<943, 256, 0, stream>>>(Af, A64, AT64);
  k_setupState<<<184, 256, 0, stream>>>(puz, p_, z_, lam_, dd_, nu_);
  k_setupB<<<324, 256, 0, stream>>>(A64, lz, bvec);

  dim3 g4(21, 64);
  for (int it = 0; it < NIT; ++it) {
    k_pre<<<64, CTHR, 0, stream>>>(A64, AT64, z_, lam_, nu_, p_, bvec, mu_, dd_, g_, rhs_);
    k_adat<<<g4, 256, 0, stream>>>(A64, dd_, ADAT);
    k_chol<<<64, CTHR, 0, stream>>>(ADAT, rhs_, dnu_);
    k_post<<<64, CTHR, 0, stream>>>(A64, dnu_, dd_, g_, mu_, z_, lam_, nu_);
  }
  k_out<<<183, 256, 0, stream>>>(z_, out);
}

// Round 7
// 27695.749 us; speedup vs baseline: 2.3770x; 2.3770x over previous
//
#include <hip/hip_runtime.h>
#include <math.h>

// ---------------- problem constants ----------------
#define BSZ   64
#define NXDIM 729
#define NXP   736          // padded (multiple of 16), pad cols are zero
#define MDIM  324
#define MP    328          // padded vector length for m-dim arrays
#define LDA   328          // ADAT leading dim (doubles)
#define EPS   0.1
#define SIG   0.1
#define NIT   30

// Cholesky blocking
#define NB    18
#define NPAN  18           // 324 / 18
#define CTHR  1024
#define PSTR  356          // P panel stride: 324 + 32 zero pad (tile reads overshoot <= +30)

// ADAT tiling: 64x64 tiles over 6x6 upper -> 21 pairs, vector f64 FMA
#define AKC   16
#define ANCH  46           // 736 / 16

typedef unsigned long long ull;

// ---------------- setup kernels ----------------

__global__ void k_setupA(const float* __restrict__ Af,
                         double* __restrict__ A64, double* __restrict__ AT64) {
  int idx = blockIdx.x * 256 + threadIdx.x;
  if (idx < MDIM * NXP) {
    int r = idx / NXP, c = idx % NXP;
    A64[idx] = (c < NXDIM) ? (double)Af[r * NXDIM + c] : 0.0;
  }
  if (idx < NXP * MP) {
    int i = idx / MP, m = idx % MP;
    AT64[idx] = (i < NXDIM && m < MDIM) ? (double)Af[m * NXDIM + i] : 0.0;
  }
}

__global__ void k_setupState(const float* __restrict__ puz,
                             double* __restrict__ p, double* __restrict__ z,
                             double* __restrict__ lam, double* __restrict__ dd,
                             double* __restrict__ nu) {
  int idx = blockIdx.x * 256 + threadIdx.x;
  if (idx >= BSZ * NXP) return;
  int b = idx / NXP, i = idx % NXP;
  p[idx]   = (i < NXDIM) ? -(double)puz[b * NXDIM + i] : 0.0;
  z[idx]   = 1.0;
  lam[idx] = 1.0;
  dd[idx]  = 0.0;              // pads (i>=729) must stay 0 for k_adat
  if (i < MP) nu[b * MP + i] = 0.0;
}

__global__ void k_setupB(const double* __restrict__ A64,
                         const float* __restrict__ lz, double* __restrict__ bvec) {
  int m = blockIdx.x, tid = threadIdx.x;
  __shared__ double red[256];
  double s = 0.0;
  for (int i = tid; i < NXDIM; i += 256)
    s += A64[m * NXP + i] * exp((double)lz[i]);
  red[tid] = s; __syncthreads();
  for (int w = 128; w > 0; w >>= 1) { if (tid < w) red[tid] += red[tid + w]; __syncthreads(); }
  if (tid == 0) bvec[m] = red[0];
}

// ---------------- per-iteration kernels ----------------

// Fused mu + stage1 (rz,rc,d,g) + rhs. One 1024-thread WG per batch.
__global__ __launch_bounds__(1024) void k_pre(const double* __restrict__ A64,
                                              const double* __restrict__ AT64,
                                              const double* __restrict__ z,
                                              const double* __restrict__ lam,
                                              const double* __restrict__ nu,
                                              const double* __restrict__ p,
                                              const double* __restrict__ bvec,
                                              double* __restrict__ mu_g,
                                              double* __restrict__ dd,
                                              double* __restrict__ g,
                                              double* __restrict__ rhs) {
  int b = blockIdx.x, tid = threadIdx.x;
  __shared__ double nus[MDIM];
  __shared__ double zs[NXDIM];
  __shared__ double dgs[NXDIM];
  __shared__ double red[CTHR];
  __shared__ double smu;
  double s = 0.0;
  for (int l = tid; l < NXDIM; l += CTHR) {
    double zv = z[b * NXP + l], lv = lam[b * NXP + l];
    zs[l] = zv; s += zv * lv;
  }
  for (int l = tid; l < MDIM; l += CTHR) nus[l] = nu[b * MP + l];
  red[tid] = s; __syncthreads();
  for (int w = 512; w > 0; w >>= 1) { if (tid < w) red[tid] += red[tid + w]; __syncthreads(); }
  if (tid == 0) { smu = red[0] / (double)NXDIM; mu_g[b] = smu; }
  __syncthreads();
  double muv = smu;
  if (tid < NXDIM) {
    int i = tid;
    double acc = 0.0;
    #pragma unroll 4
    for (int m = 0; m < MDIM; ++m) acc += A64[m * NXP + i] * nus[m];
    double zv = zs[i], lv = lam[b * NXP + i], pv = p[b * NXP + i];
    double rz = EPS * zv + pv - lv + acc;
    double rc = zv * lv - SIG * muv;
    double ddv = 1.0 / (EPS + lv / zv);
    double gv = -(rz + rc / zv);
    dd[b * NXP + i] = ddv;
    g[b * NXP + i]  = gv;
    dgs[i] = ddv * gv;
  }
  __syncthreads();
  if (tid < MDIM) {
    double a1 = 0.0, a2 = 0.0;
    #pragma unroll 4
    for (int i = 0; i < NXDIM; ++i) {
      double a = AT64[i * MP + tid];
      a1 += a * zs[i];
      a2 += a * dgs[i];
    }
    rhs[b * MP + tid] = a2 + a1 - bvec[tid];
  }
}

// ADAT[b] upper 64x64 tile pairs, vector f64 FMA. Block = 256 thr, 4x4/thread,
// strided ownership: rows {ty+16r}, cols {tx+16c} -> conflict-free LDS reads.
__global__ __launch_bounds__(256) void k_adat(const double* __restrict__ A64,
                                              const double* __restrict__ dd,
                                              double* __restrict__ ADAT) {
  int pr = blockIdx.x;   // 0..20 upper tile pairs of 6x6 tiling
  int b  = blockIdx.y;
  int ti = 0, prr = pr;
  while (prr >= 6 - ti) { prr -= 6 - ti; ti++; }
  int tj = ti + prr;
  int m0 = ti * 64, n0 = tj * 64;
  __shared__ double Sa[AKC][66];   // [k][row] transposed
  __shared__ double Sb[AKC][66];
  int tid = threadIdx.x;
  int tx = tid & 15, ty = tid >> 4;
  const double* db = dd + b * NXP;
  double acc[4][4];
  #pragma unroll
  for (int r = 0; r < 4; ++r)
    #pragma unroll
    for (int c = 0; c < 4; ++c) acc[r][c] = 0.0;

  #pragma unroll 1
  for (int ch = 0; ch < ANCH; ++ch) {
    int i0 = ch * AKC;
    __syncthreads();
    #pragma unroll
    for (int q = 0; q < 4; ++q) {
      int row = ty + q * 16;
      int mrow = m0 + row, nrow = n0 + row;
      Sa[tx][row] = (mrow < MDIM) ? A64[(size_t)mrow * NXP + i0 + tx] : 0.0;
      Sb[tx][row] = (nrow < MDIM) ? A64[(size_t)nrow * NXP + i0 + tx] * db[i0 + tx] : 0.0;
    }
    __syncthreads();
    #pragma unroll
    for (int k = 0; k < AKC; ++k) {
      double ra[4], rb[4];
      #pragma unroll
      for (int r = 0; r < 4; ++r) ra[r] = Sa[k][ty + 16 * r];
      #pragma unroll
      for (int c = 0; c < 4; ++c) rb[c] = Sb[k][tx + 16 * c];
      #pragma unroll
      for (int r = 0; r < 4; ++r)
        #pragma unroll
        for (int c = 0; c < 4; ++c) acc[r][c] += ra[r] * rb[c];
    }
  }
  double* Mb = ADAT + (size_t)b * LDA * LDA;
  #pragma unroll
  for (int r = 0; r < 4; ++r) {
    int m = m0 + ty + 16 * r;
    if (m >= MDIM) continue;
    #pragma unroll
    for (int c = 0; c < 4; ++c) {
      int n = n0 + tx + 16 * c;
      if (n < MDIM) Mb[(size_t)m * LDA + n] = acc[r][c];
    }
  }
}

// Blocked upper Cholesky (U^T U) + solve, one 1024-thread WG (16 waves) per batch.
// NB=18, fully-unrolled static-indexed recurrences (round-5 version, 441us measured).
__global__ __launch_bounds__(1024) void k_chol(double* __restrict__ ADAT,
                                               const double* __restrict__ rhs,
                                               double* __restrict__ dnu) {
  int b = blockIdx.x, tid = threadIdx.x;
  int lane = tid & 63, wid = tid >> 6;      // 16 waves
  double* Mb = ADAT + (size_t)b * LDA * LDA;
  __shared__ double P[NB][PSTR];   // panel rows U[k0+t][j], abs col idx; [324,356) zero
  __shared__ double D[NB][NB + 1]; // diagonal block
  __shared__ double yv[MDIM];      // rhs -> y -> x
  __shared__ double ivp[NB];
  __shared__ double ys[NB];

  for (int l = tid; l < NB * (PSTR - MDIM); l += CTHR) {
    int r = l / (PSTR - MDIM), c = l % (PSTR - MDIM);
    P[r][MDIM + c] = 0.0;          // zero pad columns once; never written again
  }
  for (int l = tid; l < MDIM; l += CTHR) yv[l] = rhs[b * MP + l];

  #pragma unroll 1
  for (int p = 0; p < NPAN; ++p) {
    int k0 = p * NB, t0 = k0 + NB, rem = MDIM - t0;
    __syncthreads();
    // ---- load diag block cooperatively ----
    if (tid < NB * NB) {
      int r = tid / NB, c = tid % NB;
      D[r][c] = Mb[(size_t)(k0 + r) * LDA + (k0 + c)];
    }
    __syncthreads();
    // ---- factor diag block: wave 0, shfl recurrence (no barriers inside) ----
    if (wid == 0) {
      double dreg[NB];
      #pragma unroll
      for (int r = 0; r < NB; ++r) dreg[r] = (lane < NB) ? D[r][lane] : 0.0;
      double myiv = 0.0;
      #pragma unroll
      for (int kk = 0; kk < NB; ++kk) {
        double dk = __shfl(dreg[kk], kk);
        double iv = 1.0 / sqrt(dk);
        double u  = dreg[kk] * iv;     // row kk scaled: U[kk][lane]
        dreg[kk] = u;
        if (lane == kk) myiv = iv;
        #pragma unroll
        for (int r = kk + 1; r < NB; ++r)
          dreg[r] -= __shfl(u, r) * u; // rank-1: D[r][lane] -= U[kk][r]*U[kk][lane]
      }
      if (lane < NB) {
        ivp[lane] = myiv;
        #pragma unroll
        for (int r = 0; r < NB; ++r) {
          D[r][lane] = dreg[r];
          if (r <= lane) Mb[(size_t)(k0 + r) * LDA + (k0 + lane)] = dreg[r];
        }
      }
    }
    __syncthreads();
    // ---- panel rows (triangular solves, barrier-free) + fused fwd-subst col ----
    {
      bool isY = (tid == rem);
      bool act = (tid < rem) || isY;
      int j = t0 + tid;
      if (act) {
        double val[NB];
        #pragma unroll
        for (int r = 0; r < NB; ++r) {
          double v = isY ? yv[k0 + r] : Mb[(size_t)(k0 + r) * LDA + j];
          #pragma unroll
          for (int t = 0; t < NB; ++t)
            if (t < r) v -= D[t][r] * val[t];
          v *= ivp[r];
          val[r] = v;
          if (isY) { ys[r] = v; yv[k0 + r] = v; }
          else     { P[r][j] = v; Mb[(size_t)(k0 + r) * LDA + j] = v; }
        }
      }
    }
    __syncthreads();
    if (rem <= 0) continue;
    // ---- y tail update ----
    if (tid < rem) {
      int j = t0 + tid;
      double s = yv[j];
      #pragma unroll
      for (int t = 0; t < NB; ++t) s -= P[t][j] * ys[t];
      yv[j] = s;
    }
    // ---- trailing update: 32x32 tile per wave, 4x4 regs per lane ----
    {
      int Ni = (rem + 31) >> 5;
      int cnt = Ni * (Ni + 1) / 2;
      for (int tt = wid; tt < cnt; tt += 16) {
        int a = 0, r2 = tt;
        while (r2 >= Ni - a) { r2 -= Ni - a; ++a; }
        int bb = a + r2;
        int i0 = t0 + 32 * a, j0 = t0 + 32 * bb;
        int ib = i0 + (lane >> 3);   // rows ib + 8r
        int jb = j0 + (lane & 7);    // cols jb + 8c
        bool full = (i0 + 31 < MDIM) && (j0 + 31 < MDIM);
        double cv[4][4];
        if (full) {
          #pragma unroll
          for (int r = 0; r < 4; ++r)
            #pragma unroll
            for (int c = 0; c < 4; ++c)
              cv[r][c] = Mb[(size_t)(ib + 8 * r) * LDA + (jb + 8 * c)];
        } else {
          #pragma unroll
          for (int r = 0; r < 4; ++r)
            #pragma unroll
            for (int c = 0; c < 4; ++c) {
              int i = ib + 8 * r, j = jb + 8 * c;
              cv[r][c] = (i < MDIM && j < MDIM) ? Mb[(size_t)i * LDA + j] : 0.0;
            }
        }
        #pragma unroll
        for (int t = 0; t < NB; ++t) {
          double pi[4], pj[4];
          #pragma unroll
          for (int r = 0; r < 4; ++r) pi[r] = P[t][ib + 8 * r];
          #pragma unroll
          for (int c = 0; c < 4; ++c) pj[c] = P[t][jb + 8 * c];
          #pragma unroll
          for (int r = 0; r < 4; ++r)
            #pragma unroll
            for (int c = 0; c < 4; ++c) cv[r][c] -= pi[r] * pj[c];
        }
        if (full && bb > a) {        // strictly upper tile: unguarded store
          #pragma unroll
          for (int r = 0; r < 4; ++r)
            #pragma unroll
            for (int c = 0; c < 4; ++c)
              Mb[(size_t)(ib + 8 * r) * LDA + (jb + 8 * c)] = cv[r][c];
        } else {
          #pragma unroll
          for (int r = 0; r < 4; ++r)
            #pragma unroll
            for (int c = 0; c < 4; ++c) {
              int i = ib + 8 * r, j = jb + 8 * c;
              if (i < MDIM && j < MDIM && j >= i) Mb[(size_t)i * LDA + j] = cv[r][c];
            }
        }
      }
    }
  }
  // ---- back substitution: U x = y ----
  #pragma unroll 1
  for (int p = NPAN - 1; p >= 0; --p) {
    int k0 = p * NB, t0 = k0 + NB;
    __syncthreads();
    if (tid < NB * NB) {
      int r = tid / NB, c = tid % NB;
      D[r][c] = Mb[(size_t)(k0 + r) * LDA + (k0 + c)];
    }
    __syncthreads();
    if (t0 < MDIM) {  // y[k0+r] -= sum_{j>=t0} U[k0+r][j] * x[j]
      for (int r = wid; r < NB; r += 16) {
        double s = 0.0;
        for (int j = t0 + lane; j < MDIM; j += 64)
          s += Mb[(size_t)(k0 + r) * LDA + j] * yv[j];
        for (int off = 32; off > 0; off >>= 1) s += __shfl_xor(s, off);
        if (lane == 0) yv[k0 + r] -= s;
      }
    }
    __syncthreads();
    if (tid < 64) {   // wave-0 shfl-based diagonal back-solve
      double accv = 0.0;
      for (int kk = NB - 1; kk >= 0; --kk) {
        double ad = __shfl(accv, kk);
        double xkk = (yv[k0 + kk] - ad) / D[kk][kk];
        if (lane < kk) accv += D[lane][kk] * xkk;
        if (lane == kk) yv[k0 + kk] = xkk;
      }
    }
  }
  __syncthreads();
  for (int l = tid; l < MDIM; l += CTHR) dnu[b * MP + l] = yv[l];
}

// Fused step+update: dz/dlam in registers, in-WG alpha reduction, apply.
__global__ __launch_bounds__(1024) void k_post(const double* __restrict__ A64,
                                               const double* __restrict__ dnu,
                                               const double* __restrict__ dd,
                                               const double* __restrict__ g,
                                               const double* __restrict__ mu_g,
                                               double* __restrict__ z,
                                               double* __restrict__ lam,
                                               double* __restrict__ nu) {
  int b = blockIdx.x, tid = threadIdx.x;
  int lane = tid & 63, wid = tid >> 6;
  __shared__ double ds[MDIM];
  __shared__ double wmin[16];
  __shared__ double salpha;
  for (int l = tid; l < MDIM; l += CTHR) ds[l] = dnu[b * MP + l];
  __syncthreads();
  double zv = 0.0, lv = 0.0, dzv = 0.0, dlv = 0.0;
  bool act = (tid < NXDIM);
  double inf = __builtin_inf();
  double rm = inf;
  if (act) {
    int i = tid;
    double acc = 0.0;
    #pragma unroll 4
    for (int m = 0; m < MDIM; ++m) acc += A64[m * NXP + i] * ds[m];
    zv = z[b * NXP + i]; lv = lam[b * NXP + i];
    double ddv = dd[b * NXP + i], gv = g[b * NXP + i];
    dzv = ddv * (gv - acc);
    double rc = zv * lv - SIG * mu_g[b];
    dlv = -(rc + lv * dzv) / zv;
    double r1 = (dzv < 0.0) ? (-zv / dzv) : inf;
    double r2 = (dlv < 0.0) ? (-lv / dlv) : inf;
    rm = fmin(r1, r2);
  }
  for (int off = 32; off > 0; off >>= 1) rm = fmin(rm, __shfl_xor(rm, off));
  if (lane == 0) wmin[wid] = rm;
  __syncthreads();
  if (tid == 0) {
    double a = wmin[0];
    #pragma unroll
    for (int w = 1; w < 16; ++w) a = fmin(a, wmin[w]);
    salpha = fmin(1.0, 0.99 * a);
  }
  __syncthreads();
  double a = salpha;
  if (act) {
    z[b * NXP + tid]   = zv + a * dzv;
    lam[b * NXP + tid] = lv + a * dlv;
  }
  if (tid < MDIM) nu[b * MP + tid] += a * ds[tid];
}

__global__ void k_out(const double* __restrict__ z, float* __restrict__ out) {
  int idx = blockIdx.x * 256 + threadIdx.x;
  if (idx >= BSZ * NXDIM) return;
  int b = idx / NXDIM, i = idx % NXDIM;
  out[idx] = (float)z[b * NXP + i];
}

// ---------------- host launcher ----------------

extern "C" void kernel_launch(void* const* d_in, const int* in_sizes, int n_in,
                              void* d_out, int out_size, void* d_ws, size_t ws_size,
                              hipStream_t stream) {
  const float* puz = (const float*)d_in[0];
  const float* Af  = (const float*)d_in[1];
  const float* lz  = (const float*)d_in[2];
  float* out = (float*)d_out;

  char* base = (char*)d_ws;
  size_t off = 0;
  auto alloc = [&](size_t bytes) -> void* {
    void* ptr = base + off;
    off = (off + bytes + 255) & ~(size_t)255;
    return ptr;
  };
  double* A64  = (double*)alloc((size_t)MDIM * NXP * 8);
  double* AT64 = (double*)alloc((size_t)NXP * MP * 8);
  double* p_   = (double*)alloc((size_t)BSZ * NXP * 8);
  double* z_   = (double*)alloc((size_t)BSZ * NXP * 8);
  double* lam_ = (double*)alloc((size_t)BSZ * NXP * 8);
  double* dd_  = (double*)alloc((size_t)BSZ * NXP * 8);
  double* g_   = (double*)alloc((size_t)BSZ * NXP * 8);
  double* nu_  = (double*)alloc((size_t)BSZ * MP * 8);
  double* dnu_ = (double*)alloc((size_t)BSZ * MP * 8);
  double* rhs_ = (double*)alloc((size_t)BSZ * MP * 8);
  double* bvec = (double*)alloc((size_t)MP * 8);
  double* mu_  = (double*)alloc((size_t)BSZ * 8);
  double* ADAT = (double*)alloc((size_t)BSZ * LDA * LDA * 8);
  (void)ws_size; (void)in_sizes; (void)n_in; (void)out_size;

  k_setupA<<<943, 256, 0, stream>>>(Af, A64, AT64);
  k_setupState<<<184, 256, 0, stream>>>(puz, p_, z_, lam_, dd_, nu_);
  k_setupB<<<324, 256, 0, stream>>>(A64, lz, bvec);

  dim3 g4(21, 64);
  for (int it = 0; it < NIT; ++it) {
    k_pre<<<64, CTHR, 0, stream>>>(A64, AT64, z_, lam_, nu_, p_, bvec, mu_, dd_, g_, rhs_);
    k_adat<<<g4, 256, 0, stream>>>(A64, dd_, ADAT);
    k_chol<<<64, CTHR, 0, stream>>>(ADAT, rhs_, dnu_);
    k_post<<<64, CTHR, 0, stream>>>(A64, dnu_, dd_, g_, mu_, z_, lam_, nu_);
  }
  k_out<<<183, 256, 0, stream>>>(z_, out);
}

// Round 8
// 18315.080 us; speedup vs baseline: 3.5945x; 1.5122x over previous
//
#include <hip/hip_runtime.h>
#include <math.h>

// ---------------- problem constants ----------------
#define BSZ   64
#define NXDIM 729
#define NXP   736          // padded (multiple of 16), pad cols are zero
#define MDIM  324
#define MP    328          // padded vector length for m-dim arrays
#define LDA   328          // ADAT leading dim (floats)
#define EPSF  0.1f
#define SIGF  0.1f
#define NIT   30

// Cholesky blocking
#define NB    18
#define NPAN  18           // 324 / 18
#define CTHR  1024
#define PSTR  356          // P panel stride: 324 + 32 zero pad (tile reads overshoot <= +30)

// ADAT tiling: 64x64 tiles over 6x6 upper -> 21 pairs, vector f32 FMA
#define AKC   16
#define ANCH  46           // 736 / 16

typedef unsigned long long ull;

// ---------------- setup kernels ----------------

__global__ void k_setupA(const float* __restrict__ Af,
                         float* __restrict__ A32, float* __restrict__ AT32) {
  int idx = blockIdx.x * 256 + threadIdx.x;
  if (idx < MDIM * NXP) {
    int r = idx / NXP, c = idx % NXP;
    A32[idx] = (c < NXDIM) ? Af[r * NXDIM + c] : 0.0f;
  }
  if (idx < NXP * MP) {
    int i = idx / MP, m = idx % MP;
    AT32[idx] = (i < NXDIM && m < MDIM) ? Af[m * NXDIM + i] : 0.0f;
  }
}

__global__ void k_setupState(const float* __restrict__ puz,
                             float* __restrict__ p, float* __restrict__ z,
                             float* __restrict__ lam, float* __restrict__ dd,
                             float* __restrict__ nu) {
  int idx = blockIdx.x * 256 + threadIdx.x;
  if (idx >= BSZ * NXP) return;
  int b = idx / NXP, i = idx % NXP;
  p[idx]   = (i < NXDIM) ? -puz[b * NXDIM + i] : 0.0f;
  z[idx]   = 1.0f;
  lam[idx] = 1.0f;
  dd[idx]  = 0.0f;             // pads (i>=729) must stay 0 for k_adat
  if (i < MP) nu[b * MP + i] = 0.0f;
}

__global__ void k_setupB(const float* __restrict__ A32,
                         const float* __restrict__ lz, float* __restrict__ bvec) {
  int m = blockIdx.x, tid = threadIdx.x;
  __shared__ float red[256];
  float s = 0.0f;
  for (int i = tid; i < NXDIM; i += 256)
    s += A32[m * NXP + i] * expf(lz[i]);
  red[tid] = s; __syncthreads();
  for (int w = 128; w > 0; w >>= 1) { if (tid < w) red[tid] += red[tid + w]; __syncthreads(); }
  if (tid == 0) bvec[m] = red[0];
}

// ---------------- per-iteration kernels ----------------

// Fused mu + stage1 (rz,rc,d,g) + rhs. One 1024-thread WG per batch.
__global__ __launch_bounds__(1024) void k_pre(const float* __restrict__ A32,
                                              const float* __restrict__ AT32,
                                              const float* __restrict__ z,
                                              const float* __restrict__ lam,
                                              const float* __restrict__ nu,
                                              const float* __restrict__ p,
                                              const float* __restrict__ bvec,
                                              float* __restrict__ mu_g,
                                              float* __restrict__ dd,
                                              float* __restrict__ g,
                                              float* __restrict__ rhs) {
  int b = blockIdx.x, tid = threadIdx.x;
  __shared__ float nus[MDIM];
  __shared__ float zs[NXDIM];
  __shared__ float dgs[NXDIM];
  __shared__ float red[CTHR];
  __shared__ float smu;
  float s = 0.0f;
  for (int l = tid; l < NXDIM; l += CTHR) {
    float zv = z[b * NXP + l], lv = lam[b * NXP + l];
    zs[l] = zv; s += zv * lv;
  }
  for (int l = tid; l < MDIM; l += CTHR) nus[l] = nu[b * MP + l];
  red[tid] = s; __syncthreads();
  for (int w = 512; w > 0; w >>= 1) { if (tid < w) red[tid] += red[tid + w]; __syncthreads(); }
  if (tid == 0) { smu = red[0] / (float)NXDIM; mu_g[b] = smu; }
  __syncthreads();
  float muv = smu;
  if (tid < NXDIM) {
    int i = tid;
    float acc = 0.0f;
    #pragma unroll 4
    for (int m = 0; m < MDIM; ++m) acc += A32[m * NXP + i] * nus[m];
    float zv = zs[i], lv = lam[b * NXP + i], pv = p[b * NXP + i];
    float rz = EPSF * zv + pv - lv + acc;
    float rc = zv * lv - SIGF * muv;
    float ddv = 1.0f / (EPSF + lv / zv);
    float gv = -(rz + rc / zv);
    dd[b * NXP + i] = ddv;
    g[b * NXP + i]  = gv;
    dgs[i] = ddv * gv;
  }
  __syncthreads();
  if (tid < MDIM) {
    float a1 = 0.0f, a2 = 0.0f;
    #pragma unroll 4
    for (int i = 0; i < NXDIM; ++i) {
      float a = AT32[i * MP + tid];
      a1 += a * zs[i];
      a2 += a * dgs[i];
    }
    rhs[b * MP + tid] = a2 + a1 - bvec[tid];
  }
}

// ADAT[b] upper 64x64 tile pairs, vector f32 FMA. Block = 256 thr, 4x4/thread,
// strided ownership: rows {ty+16r}, cols {tx+16c} -> conflict-free LDS reads.
__global__ __launch_bounds__(256) void k_adat(const float* __restrict__ A32,
                                              const float* __restrict__ dd,
                                              float* __restrict__ ADAT) {
  int pr = blockIdx.x;   // 0..20 upper tile pairs of 6x6 tiling
  int b  = blockIdx.y;
  int ti = 0, prr = pr;
  while (prr >= 6 - ti) { prr -= 6 - ti; ti++; }
  int tj = ti + prr;
  int m0 = ti * 64, n0 = tj * 64;
  __shared__ float Sa[AKC][66];   // [k][row] transposed
  __shared__ float Sb[AKC][66];
  int tid = threadIdx.x;
  int tx = tid & 15, ty = tid >> 4;
  const float* db = dd + b * NXP;
  float acc[4][4];
  #pragma unroll
  for (int r = 0; r < 4; ++r)
    #pragma unroll
    for (int c = 0; c < 4; ++c) acc[r][c] = 0.0f;

  #pragma unroll 1
  for (int ch = 0; ch < ANCH; ++ch) {
    int i0 = ch * AKC;
    __syncthreads();
    #pragma unroll
    for (int q = 0; q < 4; ++q) {
      int row = ty + q * 16;
      int mrow = m0 + row, nrow = n0 + row;
      Sa[tx][row] = (mrow < MDIM) ? A32[(size_t)mrow * NXP + i0 + tx] : 0.0f;
      Sb[tx][row] = (nrow < MDIM) ? A32[(size_t)nrow * NXP + i0 + tx] * db[i0 + tx] : 0.0f;
    }
    __syncthreads();
    #pragma unroll
    for (int k = 0; k < AKC; ++k) {
      float ra[4], rb[4];
      #pragma unroll
      for (int r = 0; r < 4; ++r) ra[r] = Sa[k][ty + 16 * r];
      #pragma unroll
      for (int c = 0; c < 4; ++c) rb[c] = Sb[k][tx + 16 * c];
      #pragma unroll
      for (int r = 0; r < 4; ++r)
        #pragma unroll
        for (int c = 0; c < 4; ++c) acc[r][c] += ra[r] * rb[c];
    }
  }
  float* Mb = ADAT + (size_t)b * LDA * LDA;
  #pragma unroll
  for (int r = 0; r < 4; ++r) {
    int m = m0 + ty + 16 * r;
    if (m >= MDIM) continue;
    #pragma unroll
    for (int c = 0; c < 4; ++c) {
      int n = n0 + tx + 16 * c;
      if (n < MDIM) Mb[(size_t)m * LDA + n] = acc[r][c];
    }
  }
}

// Blocked upper Cholesky (U^T U) + solve, one 1024-thread WG (16 waves) per batch.
// NB=18, fully-unrolled static-indexed recurrences (round-5 structure, f32).
__global__ __launch_bounds__(1024) void k_chol(float* __restrict__ ADAT,
                                               const float* __restrict__ rhs,
                                               float* __restrict__ dnu) {
  int b = blockIdx.x, tid = threadIdx.x;
  int lane = tid & 63, wid = tid >> 6;      // 16 waves
  float* Mb = ADAT + (size_t)b * LDA * LDA;
  __shared__ float P[NB][PSTR];   // panel rows U[k0+t][j], abs col idx; [324,356) zero
  __shared__ float D[NB][NB + 1]; // diagonal block
  __shared__ float yv[MDIM];      // rhs -> y -> x
  __shared__ float ivp[NB];
  __shared__ float ys[NB];

  for (int l = tid; l < NB * (PSTR - MDIM); l += CTHR) {
    int r = l / (PSTR - MDIM), c = l % (PSTR - MDIM);
    P[r][MDIM + c] = 0.0f;         // zero pad columns once; never written again
  }
  for (int l = tid; l < MDIM; l += CTHR) yv[l] = rhs[b * MP + l];

  #pragma unroll 1
  for (int p = 0; p < NPAN; ++p) {
    int k0 = p * NB, t0 = k0 + NB, rem = MDIM - t0;
    __syncthreads();
    // ---- load diag block cooperatively ----
    if (tid < NB * NB) {
      int r = tid / NB, c = tid % NB;
      D[r][c] = Mb[(size_t)(k0 + r) * LDA + (k0 + c)];
    }
    __syncthreads();
    // ---- factor diag block: wave 0, shfl recurrence (no barriers inside) ----
    if (wid == 0) {
      float dreg[NB];
      #pragma unroll
      for (int r = 0; r < NB; ++r) dreg[r] = (lane < NB) ? D[r][lane] : 0.0f;
      float myiv = 0.0f;
      #pragma unroll
      for (int kk = 0; kk < NB; ++kk) {
        float dk = __shfl(dreg[kk], kk);
        float iv = 1.0f / sqrtf(dk);
        float u  = dreg[kk] * iv;      // row kk scaled: U[kk][lane]
        dreg[kk] = u;
        if (lane == kk) myiv = iv;
        #pragma unroll
        for (int r = kk + 1; r < NB; ++r)
          dreg[r] -= __shfl(u, r) * u; // rank-1: D[r][lane] -= U[kk][r]*U[kk][lane]
      }
      if (lane < NB) {
        ivp[lane] = myiv;
        #pragma unroll
        for (int r = 0; r < NB; ++r) {
          D[r][lane] = dreg[r];
          if (r <= lane) Mb[(size_t)(k0 + r) * LDA + (k0 + lane)] = dreg[r];
        }
      }
    }
    __syncthreads();
    // ---- panel rows (triangular solves, barrier-free) + fused fwd-subst col ----
    {
      bool isY = (tid == rem);
      bool act = (tid < rem) || isY;
      int j = t0 + tid;
      if (act) {
        float val[NB];
        #pragma unroll
        for (int r = 0; r < NB; ++r) {
          float v = isY ? yv[k0 + r] : Mb[(size_t)(k0 + r) * LDA + j];
          #pragma unroll
          for (int t = 0; t < NB; ++t)
            if (t < r) v -= D[t][r] * val[t];
          v *= ivp[r];
          val[r] = v;
          if (isY) { ys[r] = v; yv[k0 + r] = v; }
          else     { P[r][j] = v; Mb[(size_t)(k0 + r) * LDA + j] = v; }
        }
      }
    }
    __syncthreads();
    if (rem <= 0) continue;
    // ---- y tail update ----
    if (tid < rem) {
      int j = t0 + tid;
      float s = yv[j];
      #pragma unroll
      for (int t = 0; t < NB; ++t) s -= P[t][j] * ys[t];
      yv[j] = s;
    }
    // ---- trailing update: 32x32 tile per wave, 4x4 regs per lane ----
    {
      int Ni = (rem + 31) >> 5;
      int cnt = Ni * (Ni + 1) / 2;
      for (int tt = wid; tt < cnt; tt += 16) {
        int a = 0, r2 = tt;
        while (r2 >= Ni - a) { r2 -= Ni - a; ++a; }
        int bb = a + r2;
        int i0 = t0 + 32 * a, j0 = t0 + 32 * bb;
        int ib = i0 + (lane >> 3);   // rows ib + 8r
        int jb = j0 + (lane & 7);    // cols jb + 8c
        bool full = (i0 + 31 < MDIM) && (j0 + 31 < MDIM);
        float cv[4][4];
        if (full) {
          #pragma unroll
          for (int r = 0; r < 4; ++r)
            #pragma unroll
            for (int c = 0; c < 4; ++c)
              cv[r][c] = Mb[(size_t)(ib + 8 * r) * LDA + (jb + 8 * c)];
        } else {
          #pragma unroll
          for (int r = 0; r < 4; ++r)
            #pragma unroll
            for (int c = 0; c < 4; ++c) {
              int i = ib + 8 * r, j = jb + 8 * c;
              cv[r][c] = (i < MDIM && j < MDIM) ? Mb[(size_t)i * LDA + j] : 0.0f;
            }
        }
        #pragma unroll
        for (int t = 0; t < NB; ++t) {
          float pi[4], pj[4];
          #pragma unroll
          for (int r = 0; r < 4; ++r) pi[r] = P[t][ib + 8 * r];
          #pragma unroll
          for (int c = 0; c < 4; ++c) pj[c] = P[t][jb + 8 * c];
          #pragma unroll
          for (int r = 0; r < 4; ++r)
            #pragma unroll
            for (int c = 0; c < 4; ++c) cv[r][c] -= pi[r] * pj[c];
        }
        if (full && bb > a) {        // strictly upper tile: unguarded store
          #pragma unroll
          for (int r = 0; r < 4; ++r)
            #pragma unroll
            for (int c = 0; c < 4; ++c)
              Mb[(size_t)(ib + 8 * r) * LDA + (jb + 8 * c)] = cv[r][c];
        } else {
          #pragma unroll
          for (int r = 0; r < 4; ++r)
            #pragma unroll
            for (int c = 0; c < 4; ++c) {
              int i = ib + 8 * r, j = jb + 8 * c;
              if (i < MDIM && j < MDIM && j >= i) Mb[(size_t)i * LDA + j] = cv[r][c];
            }
        }
      }
    }
  }
  // ---- back substitution: U x = y ----
  #pragma unroll 1
  for (int p = NPAN - 1; p >= 0; --p) {
    int k0 = p * NB, t0 = k0 + NB;
    __syncthreads();
    if (tid < NB * NB) {
      int r = tid / NB, c = tid % NB;
      D[r][c] = Mb[(size_t)(k0 + r) * LDA + (k0 + c)];
    }
    __syncthreads();
    if (t0 < MDIM) {  // y[k0+r] -= sum_{j>=t0} U[k0+r][j] * x[j]
      for (int r = wid; r < NB; r += 16) {
        float s = 0.0f;
        for (int j = t0 + lane; j < MDIM; j += 64)
          s += Mb[(size_t)(k0 + r) * LDA + j] * yv[j];
        for (int off = 32; off > 0; off >>= 1) s += __shfl_xor(s, off);
        if (lane == 0) yv[k0 + r] -= s;
      }
    }
    __syncthreads();
    if (tid < 64) {   // wave-0 shfl-based diagonal back-solve
      float accv = 0.0f;
      for (int kk = NB - 1; kk >= 0; --kk) {
        float ad = __shfl(accv, kk);
        float xkk = (yv[k0 + kk] - ad) / D[kk][kk];
        if (lane < kk) accv += D[lane][kk] * xkk;
        if (lane == kk) yv[k0 + kk] = xkk;
      }
    }
  }
  __syncthreads();
  for (int l = tid; l < MDIM; l += CTHR) dnu[b * MP + l] = yv[l];
}

// Fused step+update: dz/dlam in registers, in-WG alpha reduction, apply.
__global__ __launch_bounds__(1024) void k_post(const float* __restrict__ A32,
                                               const float* __restrict__ dnu,
                                               const float* __restrict__ dd,
                                               const float* __restrict__ g,
                                               const float* __restrict__ mu_g,
                                               float* __restrict__ z,
                                               float* __restrict__ lam,
                                               float* __restrict__ nu) {
  int b = blockIdx.x, tid = threadIdx.x;
  int lane = tid & 63, wid = tid >> 6;
  __shared__ float ds[MDIM];
  __shared__ float wmin[16];
  __shared__ float salpha;
  for (int l = tid; l < MDIM; l += CTHR) ds[l] = dnu[b * MP + l];
  __syncthreads();
  float zv = 0.0f, lv = 0.0f, dzv = 0.0f, dlv = 0.0f;
  bool act = (tid < NXDIM);
  float inf = __builtin_inff();
  float rm = inf;
  if (act) {
    int i = tid;
    float acc = 0.0f;
    #pragma unroll 4
    for (int m = 0; m < MDIM; ++m) acc += A32[m * NXP + i] * ds[m];
    zv = z[b * NXP + i]; lv = lam[b * NXP + i];
    float ddv = dd[b * NXP + i], gv = g[b * NXP + i];
    dzv = ddv * (gv - acc);
    float rc = zv * lv - SIGF * mu_g[b];
    dlv = -(rc + lv * dzv) / zv;
    float r1 = (dzv < 0.0f) ? (-zv / dzv) : inf;
    float r2 = (dlv < 0.0f) ? (-lv / dlv) : inf;
    rm = fminf(r1, r2);
  }
  for (int off = 32; off > 0; off >>= 1) rm = fminf(rm, __shfl_xor(rm, off));
  if (lane == 0) wmin[wid] = rm;
  __syncthreads();
  if (tid == 0) {
    float a = wmin[0];
    #pragma unroll
    for (int w = 1; w < 16; ++w) a = fminf(a, wmin[w]);
    salpha = fminf(1.0f, 0.99f * a);
  }
  __syncthreads();
  float a = salpha;
  if (act) {
    z[b * NXP + tid]   = zv + a * dzv;
    lam[b * NXP + tid] = lv + a * dlv;
  }
  if (tid < MDIM) nu[b * MP + tid] += a * ds[tid];
}

__global__ void k_out(const float* __restrict__ z, float* __restrict__ out) {
  int idx = blockIdx.x * 256 + threadIdx.x;
  if (idx >= BSZ * NXDIM) return;
  int b = idx / NXDIM, i = idx % NXDIM;
  out[idx] = z[b * NXP + i];
}

// ---------------- host launcher ----------------

extern "C" void kernel_launch(void* const* d_in, const int* in_sizes, int n_in,
                              void* d_out, int out_size, void* d_ws, size_t ws_size,
                              hipStream_t stream) {
  const float* puz = (const float*)d_in[0];
  const float* Af  = (const float*)d_in[1];
  const float* lz  = (const float*)d_in[2];
  float* out = (float*)d_out;

  char* base = (char*)d_ws;
  size_t off = 0;
  auto alloc = [&](size_t bytes) -> void* {
    void* ptr = base + off;
    off = (off + bytes + 255) & ~(size_t)255;
    return ptr;
  };
  float* A32  = (float*)alloc((size_t)MDIM * NXP * 4);
  float* AT32 = (float*)alloc((size_t)NXP * MP * 4);
  float* p_   = (float*)alloc((size_t)BSZ * NXP * 4);
  float* z_   = (float*)alloc((size_t)BSZ * NXP * 4);
  float* lam_ = (float*)alloc((size_t)BSZ * NXP * 4);
  float* dd_  = (float*)alloc((size_t)BSZ * NXP * 4);
  float* g_   = (float*)alloc((size_t)BSZ * NXP * 4);
  float* nu_  = (float*)alloc((size_t)BSZ * MP * 4);
  float* dnu_ = (float*)alloc((size_t)BSZ * MP * 4);
  float* rhs_ = (float*)alloc((size_t)BSZ * MP * 4);
  float* bvec = (float*)alloc((size_t)MP * 4);
  float* mu_  = (float*)alloc((size_t)BSZ * 4);
  float* ADAT = (float*)alloc((size_t)BSZ * LDA * LDA * 4);
  (void)ws_size; (void)in_sizes; (void)n_in; (void)out_size;

  k_setupA<<<943, 256, 0, stream>>>(Af, A32, AT32);
  k_setupState<<<184, 256, 0, stream>>>(puz, p_, z_, lam_, dd_, nu_);
  k_setupB<<<324, 256, 0, stream>>>(A32, lz, bvec);

  dim3 g4(21, 64);
  for (int it = 0; it < NIT; ++it) {
    k_pre<<<64, CTHR, 0, stream>>>(A32, AT32, z_, lam_, nu_, p_, bvec, mu_, dd_, g_, rhs_);
    k_adat<<<g4, 256, 0, stream>>>(A32, dd_, ADAT);
    k_chol<<<64, CTHR, 0, stream>>>(ADAT, rhs_, dnu_);
    k_post<<<64, CTHR, 0, stream>>>(A32, dnu_, dd_, g_, mu_, z_, lam_, nu_);
  }
  k_out<<<183, 256, 0, stream>>>(z_, out);
}